// Round 2
// baseline (2095.509 us; speedup 1.0000x reference)
//
#include <hip/hip_runtime.h>
#include <cmath>

// Problem constants (fixed by reference): B=8, N=2048, eps=0.01, 50 iters.
#define BATCH 8
#define NPT   2048
#define NPTS  (BATCH * NPT)
#define NBLK_PER_BATCH 32              // blocks per batch
#define GRID_FUSED (BATCH * NBLK_PER_BATCH)   // 256 blocks = 1 per CU
#define TPB 512                        // 8 waves
#define RPW 8                          // rows per wave (8 waves * 8 = 64 rows/block)

// exp(dual_j - 100*cost) = exp2( C*dual + P_i + P_j + S200C*dot ), P = NEG100C*|x|^2
#define C_LOG2E 1.4426950408889634f
#define NEG100C (-144.26950408889634f)     // -100 * log2(e)
#define S200C   288.53900817779268f        // 200 * log2(e)
#define INV_NEG100C (-0.0069314718055994531f) // 1/NEG100C = -ln2/100; also -2/S200C
#define EPS_LOG 1e-8f

static __device__ __forceinline__ float fast_exp2(float x) {
#if __has_builtin(__builtin_amdgcn_exp2f)
    return __builtin_amdgcn_exp2f(x);
#else
    return exp2f(x);
#endif
}

static __device__ __forceinline__ float ag_load(const float* p) {
    return __hip_atomic_load(p, __ATOMIC_RELAXED, __HIP_MEMORY_SCOPE_AGENT);
}
static __device__ __forceinline__ void ag_store(float* p, float x) {
    __hip_atomic_store(p, x, __ATOMIC_RELAXED, __HIP_MEMORY_SCOPE_AGENT);
}

// Per-batch sense-free barrier (generation counter). nb arrivals.
// Formally sound: writers -> __syncthreads -> tid0 acq_rel RMW (release chain);
// waiter tid0 acquire-load -> __syncthreads -> block threads.
static __device__ __forceinline__ void batch_barrier(int* ctr, int* gen, int nb, int g) {
    __syncthreads();
    if (threadIdx.x == 0) {
        int old = __hip_atomic_fetch_add(ctr, 1, __ATOMIC_ACQ_REL, __HIP_MEMORY_SCOPE_AGENT);
        if (old == nb - 1) {
            __hip_atomic_store(ctr, 0, __ATOMIC_RELAXED, __HIP_MEMORY_SCOPE_AGENT);
            __hip_atomic_store(gen, g, __ATOMIC_RELEASE, __HIP_MEMORY_SCOPE_AGENT);
        } else {
            int spins = 0;
            while (__hip_atomic_load(gen, __ATOMIC_ACQUIRE, __HIP_MEMORY_SCOPE_AGENT) < g) {
                __builtin_amdgcn_s_sleep(1);
                if (++spins > (1 << 20)) break;   // hang insurance; never hit in practice
            }
        }
    }
    __syncthreads();
}

// ---------------------------------------------------------------------------
// Setup: pts[p]=(x,y,z,P), P arrays, zero u/v/emd/barriers.
// ---------------------------------------------------------------------------
__global__ void setup_kernel(const float* __restrict__ x1,
                             const float* __restrict__ x2,
                             float4* __restrict__ pts1, float4* __restrict__ pts2,
                             float* __restrict__ P1, float* __restrict__ P2,
                             float* __restrict__ u, float* __restrict__ v,
                             float* __restrict__ emd, int* __restrict__ bar) {
    int p = blockIdx.x * blockDim.x + threadIdx.x;
    if (p < NPTS) {
        float a = x1[3 * p + 0], b = x1[3 * p + 1], c = x1[3 * p + 2];
        float P = NEG100C * (a * a + b * b + c * c);
        pts1[p] = make_float4(a, b, c, P);
        P1[p] = P;
        a = x2[3 * p + 0]; b = x2[3 * p + 1]; c = x2[3 * p + 2];
        P = NEG100C * (a * a + b * b + c * c);
        pts2[p] = make_float4(a, b, c, P);
        P2[p] = P;
        u[p] = 0.0f;
        v[p] = 0.0f;
    }
    if (p < BATCH) emd[p] = 0.0f;
    if (p < 1024) bar[p] = 0;
}

// ---------------------------------------------------------------------------
// Fused: 50 Sinkhorn iterations + final EMD in one persistent kernel.
// Block -> (batch = blockIdx&7 [XCD-friendly], tile = blockIdx>>3).
// LDS: both 2048-point tables (raw xyz, w = P + C*dual refreshed per half).
// ---------------------------------------------------------------------------
__global__ __launch_bounds__(TPB, 2) void fused_kernel(
        const float4* __restrict__ pts1, const float4* __restrict__ pts2,
        const float* __restrict__ P1g, const float* __restrict__ P2g,
        float* __restrict__ u, float* __restrict__ v,
        float* __restrict__ emd, int* __restrict__ bar, float log_mu) {
    __shared__ float4 T1[NPT];   // 32 KB  (x1 raw, w = P1 [+ C*u in v-halves])
    __shared__ float4 T2[NPT];   // 32 KB  (x2 raw, w = P2 [+ C*v in u-halves])

    const int b    = blockIdx.x & 7;
    const int tile = blockIdx.x >> 3;
    const int base = b * NPT;
    const int lane = threadIdx.x & 63;
    const int wave = threadIdx.x >> 6;
    const int row0 = tile * 64 + wave * RPW;

    int* ctr = bar + b * 128;        // 512B stride between batches
    int* gen = ctr + 64;

    // One-time staging of both tables.
    for (int j = threadIdx.x; j < NPT; j += TPB) {
        T1[j] = pts1[base + j];
        T2[j] = pts2[base + j];
    }
    __syncthreads();

    // Hoist this wave's 8 rows (both sides) into registers; scale folded into row.
    float rx[RPW], ry[RPW], rz[RPW], rc[RPW];   // x1 rows (u-half)
    float sx[RPW], sy[RPW], sz[RPW], sc[RPW];   // x2 rows (v-half)
#pragma unroll
    for (int r = 0; r < RPW; r++) {
        float4 a = T1[row0 + r];
        rx[r] = S200C * a.x; ry[r] = S200C * a.y; rz[r] = S200C * a.z; rc[r] = a.w;
        float4 c2 = T2[row0 + r];
        sx[r] = S200C * c2.x; sy[r] = S200C * c2.y; sz[r] = S200C * c2.z; sc[r] = c2.w;
    }
    __syncthreads();   // regs hoisted before any .w overwrite

    float uval[RPW];
    int g = 0;

    for (int it = 0; it < 50; it++) {
        // ----- u-half: u_i = log_mu - log(sum_j exp2(C*v_j + P1_i + P2_j + S*dot))
        for (int j = threadIdx.x; j < NPT; j += TPB)
            T2[j].w = fmaf(C_LOG2E, ag_load(&v[base + j]), P2g[base + j]);
        __syncthreads();
        {
            float acc[RPW];
#pragma unroll
            for (int r = 0; r < RPW; r++) acc[r] = 0.0f;
#pragma unroll 4
            for (int k = 0; k < NPT / 64; k++) {
                float4 y = T2[k * 64 + lane];
#pragma unroll
                for (int r = 0; r < RPW; r++) {
                    float t = fmaf(rx[r], y.x, fmaf(ry[r], y.y, fmaf(rz[r], y.z, rc[r])));
                    acc[r] += fast_exp2(t + y.w);
                }
            }
#pragma unroll
            for (int r = 0; r < RPW; r++) {
                float s = acc[r];
#pragma unroll
                for (int m = 32; m >= 1; m >>= 1) s += __shfl_xor(s, m, 64);
                uval[r] = log_mu - logf(s + EPS_LOG);
                if (lane == r) ag_store(&u[base + row0 + r], uval[r]);
            }
        }
        g++; batch_barrier(ctr, gen, NBLK_PER_BATCH, g);

        // ----- v-half: v_j = log_nu - log(sum_i exp2(C*u_i + P1_i + P2_j + S*dot))
        for (int j = threadIdx.x; j < NPT; j += TPB)
            T1[j].w = fmaf(C_LOG2E, ag_load(&u[base + j]), P1g[base + j]);
        __syncthreads();
        {
            float acc[RPW];
#pragma unroll
            for (int r = 0; r < RPW; r++) acc[r] = 0.0f;
#pragma unroll 4
            for (int k = 0; k < NPT / 64; k++) {
                float4 y = T1[k * 64 + lane];
#pragma unroll
                for (int r = 0; r < RPW; r++) {
                    float t = fmaf(sx[r], y.x, fmaf(sy[r], y.y, fmaf(sz[r], y.z, sc[r])));
                    acc[r] += fast_exp2(t + y.w);
                }
            }
#pragma unroll
            for (int r = 0; r < RPW; r++) {
                float s = acc[r];
#pragma unroll
                for (int m = 32; m >= 1; m >>= 1) s += __shfl_xor(s, m, 64);
                float vv = log_mu - logf(s + EPS_LOG);
                if (lane == r) ag_store(&v[base + row0 + r], vv);
            }
        }
        g++; batch_barrier(ctr, gen, NBLK_PER_BATCH, g);
    }

    // ----- final: emd[b] = sum_ij exp2(C*u_i + C*v_j + P1_i + P2_j + S*dot) * cost
    for (int j = threadIdx.x; j < NPT; j += TPB)
        T2[j].w = fmaf(C_LOG2E, ag_load(&v[base + j]), P2g[base + j]);
    __syncthreads();

    float rcc[RPW], rn1[RPW];
#pragma unroll
    for (int r = 0; r < RPW; r++) {
        rcc[r] = fmaf(C_LOG2E, uval[r], rc[r]);   // C*u_i + P1_i (final u)
        rn1[r] = rc[r] * INV_NEG100C;             // n1_i
    }
    float eacc = 0.0f;
#pragma unroll 2
    for (int k = 0; k < NPT / 64; k++) {
        float4 y = T2[k * 64 + lane];
        float n2 = P2g[base + k * 64 + lane] * INV_NEG100C;
#pragma unroll
        for (int r = 0; r < RPW; r++) {
            float sd = fmaf(rx[r], y.x, fmaf(ry[r], y.y, rz[r] * y.z)); // S200C*dot
            float cost = fmaf(INV_NEG100C, sd, rn1[r] + n2);            // n1+n2-2dot
            eacc = fmaf(fast_exp2(sd + rcc[r] + y.w), cost, eacc);
        }
    }
#pragma unroll
    for (int m = 32; m >= 1; m >>= 1) eacc += __shfl_xor(eacc, m, 64);
    if (lane == 0) atomicAdd(&emd[b], eacc);     // 8 waves/block x 32 blocks per entry
}

// ---------------------------------------------------------------------------
extern "C" void kernel_launch(void* const* d_in, const int* in_sizes, int n_in,
                              void* d_out, int out_size, void* d_ws, size_t ws_size,
                              hipStream_t stream) {
    (void)in_sizes; (void)n_in; (void)out_size; (void)ws_size;
    const float* x1 = (const float*)d_in[0];
    const float* x2 = (const float*)d_in[1];
    float* out = (float*)d_out;

    char* ws = (char*)d_ws;
    float4* pts1 = (float4*)ws;                  // NPTS float4
    float4* pts2 = pts1 + NPTS;
    float*  P1   = (float*)(pts2 + NPTS);        // NPTS floats
    float*  P2   = P1 + NPTS;
    float*  u    = P2 + NPTS;
    float*  v    = u + NPTS;
    int*    bar  = (int*)(v + NPTS);             // 1024 ints

    const float log_mu = logf(1.0f / (float)NPT + EPS_LOG);

    setup_kernel<<<(NPTS + 255) / 256, 256, 0, stream>>>(x1, x2, pts1, pts2,
                                                         P1, P2, u, v, out, bar);

    void* args[] = {&pts1, &pts2, &P1, &P2, &u, &v, &out, &bar,
                    (void*)&log_mu};
    float lm = log_mu;
    args[8] = &lm;
    hipLaunchCooperativeKernel((void*)fused_kernel, dim3(GRID_FUSED), dim3(TPB),
                               args, 0, stream);
}

// Round 6
// 1446.678 us; speedup vs baseline: 1.4485x; 1.4485x over previous
//
#include <hip/hip_runtime.h>
#include <cmath>

// Problem constants (fixed by reference): B=8, N=2048, eps=0.01, 50 iters.
#define BATCH 8
#define NPT   2048
#define NPTS  (BATCH * NPT)
#define NBLK_PER_BATCH 64                     // blocks per batch
#define GRID_FUSED (BATCH * NBLK_PER_BATCH)   // 512 blocks = 2 per CU
#define TPB 512                               // 8 waves
#define RPW 4                                 // rows per wave (8*4 = 32 rows/block)

// exp(dual_j - 100*cost) = exp2( C*dual + P_i + P_j + S200C*dot ), P = NEG100C*|x|^2
#define C_LOG2E 1.4426950408889634f
#define NEG100C (-144.26950408889634f)        // -100 * log2(e)
#define S200C   288.53900817779268f           // 200 * log2(e)
#define INV_NEG100C (-0.0069314718055994531f) // -ln2/100 ; also -2/S200C
#define EPS_LOG 1e-8f

static __device__ __forceinline__ float fast_exp2(float x) {
#if __has_builtin(__builtin_amdgcn_exp2f)
    return __builtin_amdgcn_exp2f(x);
#else
    return exp2f(x);
#endif
}

static __device__ __forceinline__ float ag_load(const float* p) {
    return __hip_atomic_load(p, __ATOMIC_RELAXED, __HIP_MEMORY_SCOPE_AGENT);
}
static __device__ __forceinline__ void ag_store(float* p, float x) {
    __hip_atomic_store(p, x, __ATOMIC_RELAXED, __HIP_MEMORY_SCOPE_AGENT);
}

// Per-batch barrier on a MONOTONE counter.
//  - __syncthreads(): all waves' dual stores vmcnt-retired + exec barrier.
//  - arrival: fetch_add RELEASE -> buffer_wbl2 (flush this XCD's dirty lines
//    to the coherence point) before the RMW lands at the coherence point.
//  - poll: relaxed fetch_add(ctr, 0) -> RMW reads true value at the coherence
//    point with NO per-poll cache invalidate (R2's acquire-poll was the
//    16 us/barrier bug).
//  - exit: one ACQUIRE fence (buffer_inv) so post-barrier dual loads can't
//    hit stale L1/L2 lines.
// NOTE (R3/R5 lesson): this barrier was never actually exercised before —
// hipLaunchCooperativeKernel silently rejected grid=512 (API occupancy calc
// caps LDS/CU below HW's 160 KB) and the error was swallowed. Launching
// non-cooperatively: 512 blocks x {64 KB LDS, <=128 VGPR} = 2 blocks/CU fits
// real HW limits, and the CP dispatches all workgroups greedily, so all
// blocks are co-resident before any spin.
static __device__ __forceinline__ void batch_barrier(int* ctr, int target) {
    __syncthreads();
    if (threadIdx.x == 0) {
        __hip_atomic_fetch_add(ctr, 1, __ATOMIC_RELEASE, __HIP_MEMORY_SCOPE_AGENT);
        int spins = 0;
        while (__hip_atomic_fetch_add(ctr, 0, __ATOMIC_RELAXED,
                                      __HIP_MEMORY_SCOPE_AGENT) < target) {
            __builtin_amdgcn_s_sleep(2);
            if (++spins > (1 << 22)) break;   // hang insurance; never hit when correct
        }
        __builtin_amdgcn_fence(__ATOMIC_ACQUIRE, "agent");
    }
    __syncthreads();
}

// ---------------------------------------------------------------------------
// Setup: pts[p]=(x,y,z,P), P arrays, zero u/v/emd/barriers.
// ---------------------------------------------------------------------------
__global__ void setup_kernel(const float* __restrict__ x1,
                             const float* __restrict__ x2,
                             float4* __restrict__ pts1, float4* __restrict__ pts2,
                             float* __restrict__ P1, float* __restrict__ P2,
                             float* __restrict__ u, float* __restrict__ v,
                             float* __restrict__ emd, int* __restrict__ bar) {
    int p = blockIdx.x * blockDim.x + threadIdx.x;
    if (p < NPTS) {
        float a = x1[3 * p + 0], b = x1[3 * p + 1], c = x1[3 * p + 2];
        float P = NEG100C * (a * a + b * b + c * c);
        pts1[p] = make_float4(a, b, c, P);
        P1[p] = P;
        a = x2[3 * p + 0]; b = x2[3 * p + 1]; c = x2[3 * p + 2];
        P = NEG100C * (a * a + b * b + c * c);
        pts2[p] = make_float4(a, b, c, P);
        P2[p] = P;
        u[p] = 0.0f;
        v[p] = 0.0f;
    }
    if (p < BATCH) emd[p] = 0.0f;
    if (p < 1024) bar[p] = 0;
}

// ---------------------------------------------------------------------------
// Fused persistent kernel: 50 Sinkhorn iterations + final EMD.
// batch = blockIdx>>6, tile = blockIdx&63. 2 blocks/CU co-resident; the two
// resident blocks are 256 apart in blockIdx -> batches 4 apart -> their
// barriers are decoupled, so one computes while the other waits.
// ---------------------------------------------------------------------------
__global__ __launch_bounds__(TPB, 4) void fused_kernel(
        const float4* __restrict__ pts1, const float4* __restrict__ pts2,
        const float* __restrict__ P1g, const float* __restrict__ P2g,
        float* __restrict__ u, float* __restrict__ v,
        float* __restrict__ emd, int* __restrict__ bar, float log_mu) {
    __shared__ float4 T1[NPT];   // 32 KB  (x1 raw, w = P1 + C*u in v-halves)
    __shared__ float4 T2[NPT];   // 32 KB  (x2 raw, w = P2 + C*v in u-halves)

    const int b    = blockIdx.x >> 6;
    const int tile = blockIdx.x & 63;
    const int base = b * NPT;
    const int lane = threadIdx.x & 63;
    const int wave = threadIdx.x >> 6;
    const int row0 = tile * 32 + wave * RPW;

    int* ctr = bar + b * 32;     // 128 B apart per batch

    // One-time table staging + per-thread staging constants in registers.
    float p1r[NPT / TPB], p2r[NPT / TPB];
#pragma unroll
    for (int s = 0; s < NPT / TPB; s++) {
        int j = threadIdx.x + s * TPB;
        T1[j] = pts1[base + j];
        T2[j] = pts2[base + j];
        p1r[s] = P1g[base + j];
        p2r[s] = P2g[base + j];
    }
    __syncthreads();

    // Hoist this wave's rows (both sides) into registers, scale folded in.
    float rx[RPW], ry[RPW], rz[RPW], rc[RPW];   // x1 rows (u-half)
    float sx[RPW], sy[RPW], sz[RPW], sc[RPW];   // x2 rows (v-half)
#pragma unroll
    for (int r = 0; r < RPW; r++) {
        float4 a = T1[row0 + r];
        rx[r] = S200C * a.x; ry[r] = S200C * a.y; rz[r] = S200C * a.z; rc[r] = a.w;
        float4 c2 = T2[row0 + r];
        sx[r] = S200C * c2.x; sy[r] = S200C * c2.y; sz[r] = S200C * c2.z; sc[r] = c2.w;
    }
    __syncthreads();   // hoist reads complete before any .w overwrite

    float uval[RPW];
    int g = 0;

    for (int it = 0; it < 50; it++) {
        // ----- u-half: u_i = log_mu - log(sum_j exp2(C*v_j + P1_i + P2_j + S*dot))
#pragma unroll
        for (int s = 0; s < NPT / TPB; s++) {
            int j = threadIdx.x + s * TPB;
            T2[j].w = fmaf(C_LOG2E, ag_load(&v[base + j]), p2r[s]);
        }
        __syncthreads();
        {
            float acc[RPW];
#pragma unroll
            for (int r = 0; r < RPW; r++) acc[r] = 0.0f;
#pragma unroll 2
            for (int k = 0; k < NPT / 64; k++) {
                float4 y = T2[k * 64 + lane];
#pragma unroll
                for (int r = 0; r < RPW; r++) {
                    float t = fmaf(rx[r], y.x, fmaf(ry[r], y.y, fmaf(rz[r], y.z, rc[r])));
                    acc[r] += fast_exp2(t + y.w);
                }
            }
#pragma unroll
            for (int r = 0; r < RPW; r++) {
                float s = acc[r];
#pragma unroll
                for (int m = 32; m >= 1; m >>= 1) s += __shfl_xor(s, m, 64);
                uval[r] = log_mu - logf(s + EPS_LOG);
                if (lane == r) ag_store(&u[base + row0 + r], uval[r]);
            }
        }
        g++; batch_barrier(ctr, g * NBLK_PER_BATCH);

        // ----- v-half: v_j = log_nu - log(sum_i exp2(C*u_i + P1_i + P2_j + S*dot))
#pragma unroll
        for (int s = 0; s < NPT / TPB; s++) {
            int j = threadIdx.x + s * TPB;
            T1[j].w = fmaf(C_LOG2E, ag_load(&u[base + j]), p1r[s]);
        }
        __syncthreads();
        {
            float acc[RPW];
#pragma unroll
            for (int r = 0; r < RPW; r++) acc[r] = 0.0f;
#pragma unroll 2
            for (int k = 0; k < NPT / 64; k++) {
                float4 y = T1[k * 64 + lane];
#pragma unroll
                for (int r = 0; r < RPW; r++) {
                    float t = fmaf(sx[r], y.x, fmaf(sy[r], y.y, fmaf(sz[r], y.z, sc[r])));
                    acc[r] += fast_exp2(t + y.w);
                }
            }
#pragma unroll
            for (int r = 0; r < RPW; r++) {
                float s = acc[r];
#pragma unroll
                for (int m = 32; m >= 1; m >>= 1) s += __shfl_xor(s, m, 64);
                float vv = log_mu - logf(s + EPS_LOG);
                if (lane == r) ag_store(&v[base + row0 + r], vv);
            }
        }
        g++; batch_barrier(ctr, g * NBLK_PER_BATCH);
    }

    // ----- final: emd[b] = sum_ij exp2(C*u_i + C*v_j + P1_i + P2_j + S*dot) * cost
#pragma unroll
    for (int s = 0; s < NPT / TPB; s++) {
        int j = threadIdx.x + s * TPB;
        T2[j].w = fmaf(C_LOG2E, ag_load(&v[base + j]), p2r[s]);
    }
    __syncthreads();

    float rcc[RPW], rn1[RPW];
#pragma unroll
    for (int r = 0; r < RPW; r++) {
        rcc[r] = fmaf(C_LOG2E, uval[r], rc[r]);   // C*u_i + P1_i (final u)
        rn1[r] = rc[r] * INV_NEG100C;             // n1_i
    }
    float eacc = 0.0f;
#pragma unroll 2
    for (int k = 0; k < NPT / 64; k++) {
        float4 y = T2[k * 64 + lane];
        float n2 = P2g[base + k * 64 + lane] * INV_NEG100C;
#pragma unroll
        for (int r = 0; r < RPW; r++) {
            float sd = fmaf(rx[r], y.x, fmaf(ry[r], y.y, rz[r] * y.z)); // S200C*dot
            float cost = fmaf(INV_NEG100C, sd, rn1[r] + n2);            // n1+n2-2dot
            eacc = fmaf(fast_exp2(sd + rcc[r] + y.w), cost, eacc);
        }
    }
#pragma unroll
    for (int m = 32; m >= 1; m >>= 1) eacc += __shfl_xor(eacc, m, 64);
    if (lane == 0) atomicAdd(&emd[b], eacc);   // device-scope RMW: cross-XCD safe

    (void)tile;
}

// ---------------------------------------------------------------------------
extern "C" void kernel_launch(void* const* d_in, const int* in_sizes, int n_in,
                              void* d_out, int out_size, void* d_ws, size_t ws_size,
                              hipStream_t stream) {
    (void)in_sizes; (void)n_in; (void)out_size; (void)ws_size;
    const float* x1 = (const float*)d_in[0];
    const float* x2 = (const float*)d_in[1];
    float* out = (float*)d_out;

    char* ws = (char*)d_ws;
    float4* pts1 = (float4*)ws;                  // NPTS float4
    float4* pts2 = pts1 + NPTS;
    float*  P1   = (float*)(pts2 + NPTS);        // NPTS floats
    float*  P2   = P1 + NPTS;
    float*  u    = P2 + NPTS;
    float*  v    = u + NPTS;
    int*    bar  = (int*)(v + NPTS);             // 1024 ints

    const float lm = logf(1.0f / (float)NPT + EPS_LOG);

    setup_kernel<<<(NPTS + 255) / 256, 256, 0, stream>>>(x1, x2, pts1, pts2,
                                                         P1, P2, u, v, out, bar);

    // Non-cooperative persistent launch: all 512 blocks fit the device at
    // once (2/CU: 128 KB LDS <= 160 KB, VGPR <= 128), so the batch barriers
    // cannot deadlock. The cooperative-launch API rejected this grid against
    // its conservative occupancy model (that was R3/R5's silent no-launch).
    fused_kernel<<<dim3(GRID_FUSED), dim3(TPB), 0, stream>>>(
        pts1, pts2, P1, P2, u, v, out, bar, lm);
}